// Round 16
// baseline (208.328 us; speedup 1.0000x reference)
//
#include <hip/hip_runtime.h>
#include <math.h>

#define NIN 91392        // 17*21*16*16
#define DIN 8
#define DOUT 16
#define NCHUNK (NIN / 8) // 11424 chunks of 8 n
#define GRID_P 768       // 3 blocks/CU (48 KB LDS double-buffer)
#define TPB 512          // 8 waves

// async global->LDS width16: dest = lane-uniform base + lane*16; src per-lane
#define GLD_LDS16(gp, lp) __builtin_amdgcn_global_load_lds(                    \
    (const __attribute__((address_space(1))) float*)(gp),                      \
    (__attribute__((address_space(3))) float*)(lp), 16, 0, 0)

// ---- shared round-staging issue (R15-verified) ----
__device__ __forceinline__ void issue_round(
    const float* __restrict__ x, const float* __restrict__ W,
    float* lds, int bid, int grid, int k, int lane, int wave)
{
    const int wR_half = lane >> 5;
    const int wFlo = (lane & 31) * 4;
    const int xb = (wave & 3) * 4 + (lane >> 4);
    const int xu = (lane & 15) ^ (xb & 7);
    const int xs = wave >> 2;
    const int bufb = k & 1;
    {   const int m = 2*wave; const int s = m>>3, p = m&7;
        int c_ = bid + (2*k + s) * grid; if (c_ >= NCHUNK) c_ = bid;
        const int R = 2*p + wR_half;
        GLD_LDS16(W + (size_t)(R>>3)*((size_t)NIN*128)
                    + (size_t)(c_*8 + (R&7))*128 + wFlo,
                  lds + bufb*4096 + s*2048 + p*256);
    }
    {   const int m = 2*wave+1; const int s = m>>3, p = m&7;
        int c_ = bid + (2*k + s) * grid; if (c_ >= NCHUNK) c_ = bid;
        const int R = 2*p + wR_half;
        GLD_LDS16(W + (size_t)(R>>3)*((size_t)NIN*128)
                    + (size_t)(c_*8 + (R&7))*128 + wFlo,
                  lds + bufb*4096 + s*2048 + p*256);
    }
    {   int c_ = bid + (2*k + xs) * grid; if (c_ >= NCHUNK) c_ = bid;
        GLD_LDS16(x + (size_t)xb*((size_t)NIN*8) + (size_t)c_*64 + xu*4,
                  lds + 8192 + bufb*2048 + xs*1024 + (wave&3)*256);
    }
}

// ---- REAL pass kernel: byte-identical logic to R15 (verified, 143.5us) ----
template<int PASS>
__global__ __launch_bounds__(TPB) void caps_pass(
    const float* __restrict__ x, const float* __restrict__ W,
    const float* __restrict__ vin, float* __restrict__ part, int grid)
{
    const int t = threadIdx.x;
    const int lane = t & 63;
    const int wave = t >> 6;
    const int og = lane & 3;
    const int j  = (lane >> 2) & 1;
    const int b0 = lane >> 3;
    const int bid = blockIdx.x;

    __shared__ __align__(16) float lds[12288];

    const float sgn = j ? -1.f : 1.f;

    float4 vinA, vinB;
    if (PASS > 0) {
        float4 a = *(const float4*)(vin + b0 * 32 + j * 16 + og * 4);
        float4 c = *(const float4*)(vin + (b0 + 8) * 32 + j * 16 + og * 4);
        vinA = make_float4(sgn*a.x, sgn*a.y, sgn*a.z, sgn*a.w);
        vinB = make_float4(sgn*c.x, sgn*c.y, sgn*c.z, sgn*c.w);
    }

    float4 accA = make_float4(0.f,0.f,0.f,0.f);
    float4 accB = make_float4(0.f,0.f,0.f,0.f);

    const int R_rounds = (NCHUNK + 2*grid - 1) / (2*grid);

    issue_round(x, W, lds, bid, grid, 0, lane, wave);
    issue_round(x, W, lds, bid, grid, 1, lane, wave);

    for (int k = 0; k < R_rounds; ++k) {
        asm volatile("s_waitcnt vmcnt(3)" ::: "memory");
        __builtin_amdgcn_s_barrier();

        const int bufb = k & 1;
        #pragma unroll
        for (int s = 0; s < 2; ++s) {
            const int c = bid + (2*k + s) * grid;
            if (c < NCHUNK) {
                const float* wrow = lds + bufb*4096 + s*2048
                                  + (j*8 + wave)*128 + og*4;
                const float* xrg  = lds + 8192 + bufb*2048 + s*1024;
                const int u0i = wave * 2;
                const int swz = (b0 & 7);
                const float4 a0 = *(const float4*)(xrg + b0*64     + ((u0i  )^swz)*4);
                const float4 a1 = *(const float4*)(xrg + b0*64     + ((u0i+1)^swz)*4);
                const float4 c0v= *(const float4*)(xrg + (b0+8)*64 + ((u0i  )^swz)*4);
                const float4 c1v= *(const float4*)(xrg + (b0+8)*64 + ((u0i+1)^swz)*4);
                const float xA[8] = {a0.x,a0.y,a0.z,a0.w,a1.x,a1.y,a1.z,a1.w};
                const float xB[8] = {c0v.x,c0v.y,c0v.z,c0v.w,c1v.x,c1v.y,c1v.z,c1v.w};

                float4 u0 = make_float4(0.f,0.f,0.f,0.f);
                float4 u1 = make_float4(0.f,0.f,0.f,0.f);
                #pragma unroll
                for (int i = 0; i < DIN; ++i) {
                    const float4 w4 = *(const float4*)(wrow + i*16);
                    u0.x += xA[i]*w4.x; u0.y += xA[i]*w4.y;
                    u0.z += xA[i]*w4.z; u0.w += xA[i]*w4.w;
                    u1.x += xB[i]*w4.x; u1.y += xB[i]*w4.y;
                    u1.z += xB[i]*w4.z; u1.w += xB[i]*w4.w;
                }

                if (PASS == 0) {
                    accA.x += u0.x; accA.y += u0.y; accA.z += u0.z; accA.w += u0.w;
                    accB.x += u1.x; accB.y += u1.y; accB.z += u1.z; accB.w += u1.w;
                } else {
                    float m0 = vinA.x*u0.x + vinA.y*u0.y + vinA.z*u0.z + vinA.w*u0.w;
                    float m1 = vinB.x*u1.x + vinB.y*u1.y + vinB.z*u1.z + vinB.w*u1.w;
                    m0 += __shfl_xor(m0, 1);  m1 += __shfl_xor(m1, 1);
                    m0 += __shfl_xor(m0, 2);  m1 += __shfl_xor(m1, 2);
                    m0 += __shfl_xor(m0, 4);  m1 += __shfl_xor(m1, 4);
                    const float cA = __builtin_amdgcn_rcpf(1.f + __expf(-sgn * m0));
                    const float cB = __builtin_amdgcn_rcpf(1.f + __expf(-sgn * m1));
                    accA.x += cA*u0.x; accA.y += cA*u0.y;
                    accA.z += cA*u0.z; accA.w += cA*u0.w;
                    accB.x += cB*u1.x; accB.y += cB*u1.y;
                    accB.z += cB*u1.z; accB.w += cB*u1.w;
                }
            }
        }
        asm volatile("s_waitcnt lgkmcnt(0)" ::: "memory");
        __builtin_amdgcn_s_barrier();
        issue_round(x, W, lds, bid, grid, k + 2, lane, wave);
    }

    asm volatile("s_waitcnt vmcnt(0)" ::: "memory");
    __syncthreads();

    {
        float* sl = lds + wave * 576 + lane * 9;
        sl[0]=accA.x; sl[1]=accA.y; sl[2]=accA.z; sl[3]=accA.w;
        sl[4]=accB.x; sl[5]=accB.y; sl[6]=accB.z; sl[7]=accB.w;
    }
    __syncthreads();
    if (t < 64) {
        float s[8];
        #pragma unroll
        for (int q = 0; q < 8; ++q) s[q] = 0.f;
        #pragma unroll
        for (int w = 0; w < 8; ++w) {
            const float* p = lds + w * 576 + t * 9;
            #pragma unroll
            for (int q = 0; q < 8; ++q) s[q] += p[q];
        }
        const int tb0 = t >> 3, tj = (t >> 2) & 1, tog = t & 3;
        #pragma unroll
        for (int q = 0; q < 4; ++q) {
            part[(size_t)(tb0*32 + tj*16 + tog*4 + q) * grid + bid] = s[q];
            part[(size_t)((tb0+8)*32 + tj*16 + tog*4 + q) * grid + bid] = s[4+q];
        }
    }
}

// ---- ABLATION A: staging skeleton only (DMA + waits + barriers) ----
__global__ __launch_bounds__(TPB) void abl_dma(
    const float* __restrict__ x, const float* __restrict__ W,
    float* __restrict__ scratch, int grid)
{
    const int t = threadIdx.x;
    const int lane = t & 63, wave = t >> 6;
    const int bid = blockIdx.x;
    __shared__ __align__(16) float lds[12288];

    const int R_rounds = (NCHUNK + 2*grid - 1) / (2*grid);
    issue_round(x, W, lds, bid, grid, 0, lane, wave);
    issue_round(x, W, lds, bid, grid, 1, lane, wave);
    for (int k = 0; k < R_rounds; ++k) {
        asm volatile("s_waitcnt vmcnt(3)" ::: "memory");
        __builtin_amdgcn_s_barrier();
        // (no DS reads / no math)
        __builtin_amdgcn_s_barrier();
        issue_round(x, W, lds, bid, grid, k + 2, lane, wave);
    }
    asm volatile("s_waitcnt vmcnt(0)" ::: "memory");
    __syncthreads();
    scratch[(size_t)bid * TPB + t] = lds[t];   // keep LDS observable
}

// ---- ABLATION B: DS+VALU from zeroed LDS, no DMA ----
__global__ __launch_bounds__(TPB) void abl_nodma(
    float* __restrict__ scratch, int grid)
{
    const int t = threadIdx.x;
    const int lane = t & 63, wave = t >> 6;
    const int og = lane & 3, j = (lane >> 2) & 1, b0 = lane >> 3;
    const int bid = blockIdx.x;
    __shared__ __align__(16) float lds[12288];
    #pragma unroll
    for (int r = 0; r < 24; ++r) lds[r * TPB + t] = 0.f;
    __syncthreads();

    const float sgn = j ? -1.f : 1.f;
    const float4 vinA = make_float4(sgn, sgn, sgn, sgn);
    const float4 vinB = vinA;
    float4 accA = make_float4(0.f,0.f,0.f,0.f);
    float4 accB = make_float4(0.f,0.f,0.f,0.f);

    const int R_rounds = (NCHUNK + 2*grid - 1) / (2*grid);
    for (int k = 0; k < R_rounds; ++k) {
        __builtin_amdgcn_s_barrier();
        const int bufb = k & 1;
        #pragma unroll
        for (int s = 0; s < 2; ++s) {
            const int c = bid + (2*k + s) * grid;
            if (c < NCHUNK) {
                const float* wrow = lds + bufb*4096 + s*2048 + (j*8+wave)*128 + og*4;
                const float* xrg  = lds + 8192 + bufb*2048 + s*1024;
                const int u0i = wave * 2, swz = (b0 & 7);
                const float4 a0 = *(const float4*)(xrg + b0*64     + ((u0i  )^swz)*4);
                const float4 a1 = *(const float4*)(xrg + b0*64     + ((u0i+1)^swz)*4);
                const float4 c0v= *(const float4*)(xrg + (b0+8)*64 + ((u0i  )^swz)*4);
                const float4 c1v= *(const float4*)(xrg + (b0+8)*64 + ((u0i+1)^swz)*4);
                const float xA[8] = {a0.x,a0.y,a0.z,a0.w,a1.x,a1.y,a1.z,a1.w};
                const float xB[8] = {c0v.x,c0v.y,c0v.z,c0v.w,c1v.x,c1v.y,c1v.z,c1v.w};
                float4 u0 = make_float4(0.f,0.f,0.f,0.f);
                float4 u1 = make_float4(0.f,0.f,0.f,0.f);
                #pragma unroll
                for (int i = 0; i < DIN; ++i) {
                    const float4 w4 = *(const float4*)(wrow + i*16);
                    u0.x += xA[i]*w4.x; u0.y += xA[i]*w4.y;
                    u0.z += xA[i]*w4.z; u0.w += xA[i]*w4.w;
                    u1.x += xB[i]*w4.x; u1.y += xB[i]*w4.y;
                    u1.z += xB[i]*w4.z; u1.w += xB[i]*w4.w;
                }
                float m0 = vinA.x*u0.x + vinA.y*u0.y + vinA.z*u0.z + vinA.w*u0.w;
                float m1 = vinB.x*u1.x + vinB.y*u1.y + vinB.z*u1.z + vinB.w*u1.w;
                m0 += __shfl_xor(m0, 1);  m1 += __shfl_xor(m1, 1);
                m0 += __shfl_xor(m0, 2);  m1 += __shfl_xor(m1, 2);
                m0 += __shfl_xor(m0, 4);  m1 += __shfl_xor(m1, 4);
                const float cA = __builtin_amdgcn_rcpf(1.f + __expf(-sgn * m0));
                const float cB = __builtin_amdgcn_rcpf(1.f + __expf(-sgn * m1));
                accA.x += cA*u0.x; accA.y += cA*u0.y;
                accA.z += cA*u0.z; accA.w += cA*u0.w;
                accB.x += cB*u1.x; accB.y += cB*u1.y;
                accB.z += cB*u1.z; accB.w += cB*u1.w;
            }
        }
        asm volatile("s_waitcnt lgkmcnt(0)" ::: "memory");
        __builtin_amdgcn_s_barrier();
    }
    scratch[(size_t)bid * TPB + t] =
        accA.x+accA.y+accA.z+accA.w+accB.x+accB.y+accB.z+accB.w;
}

// ---- ABLATION C: pure VALU chain (no memory) ----
__global__ __launch_bounds__(TPB) void abl_valu(
    float* __restrict__ scratch, int grid)
{
    const int t = threadIdx.x;
    const int lane = t & 63, wave = t >> 6;
    const int j = (lane >> 2) & 1;
    const int bid = blockIdx.x;
    __shared__ float lds[12288];     // mirror LDS footprint for occupancy
    lds[t] = 0.f;
    __syncthreads();

    const float sgn = j ? -1.f : 1.f;
    const float4 vinA = make_float4(sgn, sgn, sgn, sgn);
    float seedv = (float)(lane + wave) * 1e-3f + 1e-2f;
    float4 accA = make_float4(0.f,0.f,0.f,0.f);
    float4 accB = make_float4(0.f,0.f,0.f,0.f);

    const int R_rounds = (NCHUNK + 2*grid - 1) / (2*grid);
    for (int k = 0; k < R_rounds; ++k) {
        __builtin_amdgcn_s_barrier();
        #pragma unroll
        for (int s = 0; s < 2; ++s) {
            const int c = bid + (2*k + s) * grid;
            if (c < NCHUNK) {
                float xA[8], xB[8];
                #pragma unroll
                for (int i = 0; i < 8; ++i) { xA[i] = seedv + i; xB[i] = seedv - i; }
                float4 u0 = make_float4(0.f,0.f,0.f,0.f);
                float4 u1 = make_float4(0.f,0.f,0.f,0.f);
                #pragma unroll
                for (int i = 0; i < DIN; ++i) {
                    const float4 w4 = make_float4(seedv, seedv+1.f, seedv+2.f, seedv+3.f);
                    u0.x += xA[i]*w4.x; u0.y += xA[i]*w4.y;
                    u0.z += xA[i]*w4.z; u0.w += xA[i]*w4.w;
                    u1.x += xB[i]*w4.x; u1.y += xB[i]*w4.y;
                    u1.z += xB[i]*w4.z; u1.w += xB[i]*w4.w;
                }
                float m0 = vinA.x*u0.x + vinA.y*u0.y + vinA.z*u0.z + vinA.w*u0.w;
                float m1 = vinA.x*u1.x + vinA.y*u1.y + vinA.z*u1.z + vinA.w*u1.w;
                m0 += __shfl_xor(m0, 1);  m1 += __shfl_xor(m1, 1);
                m0 += __shfl_xor(m0, 2);  m1 += __shfl_xor(m1, 2);
                m0 += __shfl_xor(m0, 4);  m1 += __shfl_xor(m1, 4);
                const float cA = __builtin_amdgcn_rcpf(1.f + __expf(-sgn * m0));
                const float cB = __builtin_amdgcn_rcpf(1.f + __expf(m1));
                accA.x += cA*u0.x; accA.y += cA*u0.y;
                accA.z += cA*u0.z; accA.w += cA*u0.w;
                accB.x += cB*u1.x; accB.y += cB*u1.y;
                accB.z += cB*u1.z; accB.w += cB*u1.w;
                seedv = accA.x * 1e-7f + 1e-2f;   // serial dep across rounds
            }
        }
        __builtin_amdgcn_s_barrier();
    }
    scratch[(size_t)bid * TPB + t] =
        accA.x+accA.y+accA.z+accA.w+accB.x+accB.y+accB.z+accB.w + lds[t];
}

// ---- reduce (unchanged, verified) ----
template<int PASS>
__global__ __launch_bounds__(256) void caps_reduce(
    const float* __restrict__ part, const float* __restrict__ vprev,
    float* __restrict__ vout, int gridA)
{
    const int blk = blockIdx.x;
    const int b = blk >> 1, j = blk & 1;
    const int t = threadIdx.x;
    const int o = t & 15;
    const int ch = t >> 4;
    const size_t base = ((size_t)b * 32 + j * 16 + o) * gridA;
    float s = 0.f;
    for (int g = ch; g < gridA; g += 16) s += part[base + g];
    __shared__ float red[256];
    red[t] = s;
    __syncthreads();
    if (t < 16) {
        float sv = 0.f;
        #pragma unroll
        for (int c = 0; c < 16; ++c) sv += red[c * 16 + t];
        if (PASS == 0) sv *= 0.5f;
        float sq = sv * sv;
        sq += __shfl_xor(sq, 1);
        sq += __shfl_xor(sq, 2);
        sq += __shfl_xor(sq, 4);
        sq += __shfl_xor(sq, 8);
        const float sn = sq;
        float v = sv * sn / ((1.f + sn) * sqrtf(sn + 1e-7f));
        if (PASS == 1) v += vprev[b * 32 + j * 16 + o];
        vout[b * 32 + j * 16 + o] = v;
    }
}

extern "C" void kernel_launch(void* const* d_in, const int* in_sizes, int n_in,
                              void* d_out, int out_size, void* d_ws, size_t ws_size,
                              hipStream_t stream) {
    const float* x = (const float*)d_in[0];
    const float* W = (const float*)d_in[1];
    float* out = (float*)d_out;

    // part (GRID*512) + v0/vsum (4KB) + scratch (GRID*512)
    size_t maxg = (ws_size - 8192) / (2 * 512 * sizeof(float));
    int GRID = (int)(maxg < GRID_P ? maxg : GRID_P);
    if (GRID < 1) GRID = 1;

    float* part    = (float*)d_ws;
    float* v0      = part + (size_t)512 * GRID;
    float* vsum    = v0 + 512;
    float* scratch = vsum + 512;

    // real pipeline (R15-identical)
    caps_pass<0><<<GRID, TPB, 0, stream>>>(x, W, nullptr, part, GRID);
    caps_reduce<0><<<32, 256, 0, stream>>>(part, nullptr, v0, GRID);
    caps_pass<1><<<GRID, TPB, 0, stream>>>(x, W, v0, part, GRID);
    caps_reduce<1><<<32, 256, 0, stream>>>(part, v0, vsum, GRID);
    caps_pass<2><<<GRID, TPB, 0, stream>>>(x, W, vsum, part, GRID);
    caps_reduce<2><<<32, 256, 0, stream>>>(part, nullptr, out, GRID);

    // ablation probes (scratch only; outputs unused)
    abl_dma  <<<GRID, TPB, 0, stream>>>(x, W, scratch, GRID);
    abl_nodma<<<GRID, TPB, 0, stream>>>(scratch, GRID);
    abl_valu <<<GRID, TPB, 0, stream>>>(scratch, GRID);
}

// Round 17
// 129.913 us; speedup vs baseline: 1.6036x; 1.6036x over previous
//
#include <hip/hip_runtime.h>
#include <math.h>

#define NIN 91392        // 17*21*16*16
#define DIN 8
#define DOUT 16
#define NCHUNK (NIN / 8) // 11424 chunks of 8 n
#define GRID_P 768       // 3 blocks/CU (48 KB LDS double-buffer)
#define TPB 512          // 8 waves

typedef float f32x4 __attribute__((ext_vector_type(4)));

// async global->LDS width16: dest = lane-uniform base + lane*16; src per-lane
#define GLD_LDS16(gp, lp) __builtin_amdgcn_global_load_lds(                    \
    (const __attribute__((address_space(1))) float*)(gp),                      \
    (__attribute__((address_space(3))) float*)(lp), 16, 0, 0)

// inline-asm LDS read: NO memory clobber -> compiler sees no dependency on
// the global_load_lds writes, so it cannot insert its own vmcnt(0) drain
// (R16 ablation: staging+compute were perfectly ADDITIVE = compiler was
// draining the whole DMA queue before every compute phase). Ordering vs the
// DMA protocol is carried by our explicit vmcnt(3)/s_barrier (volatile asm
// order is preserved), data arrival by lgkmcnt(0)+sched_barrier (rule #18).
#define DSR128(dst, pf)                                                        \
    asm volatile("ds_read_b128 %0, %1" : "=v"(dst)                             \
        : "v"((unsigned)(__SIZE_TYPE__)                                        \
              (const __attribute__((address_space(3))) float*)(pf)))

// ---- round staging (R15-verified addressing) ----
__device__ __forceinline__ void issue_round(
    const float* __restrict__ x, const float* __restrict__ W,
    float* lds, int bid, int grid, int k, int lane, int wave)
{
    const int wR_half = lane >> 5;
    const int wFlo = (lane & 31) * 4;
    const int xb = (wave & 3) * 4 + (lane >> 4);
    const int xu = (lane & 15) ^ (xb & 7);
    const int xs = wave >> 2;
    const int bufb = k & 1;
    {   const int m = 2*wave; const int s = m>>3, p = m&7;
        int c_ = bid + (2*k + s) * grid; if (c_ >= NCHUNK) c_ = bid;
        const int R = 2*p + wR_half;
        GLD_LDS16(W + (size_t)(R>>3)*((size_t)NIN*128)
                    + (size_t)(c_*8 + (R&7))*128 + wFlo,
                  lds + bufb*4096 + s*2048 + p*256);
    }
    {   const int m = 2*wave+1; const int s = m>>3, p = m&7;
        int c_ = bid + (2*k + s) * grid; if (c_ >= NCHUNK) c_ = bid;
        const int R = 2*p + wR_half;
        GLD_LDS16(W + (size_t)(R>>3)*((size_t)NIN*128)
                    + (size_t)(c_*8 + (R&7))*128 + wFlo,
                  lds + bufb*4096 + s*2048 + p*256);
    }
    {   int c_ = bid + (2*k + xs) * grid; if (c_ >= NCHUNK) c_ = bid;
        GLD_LDS16(x + (size_t)xb*((size_t)NIN*8) + (size_t)c_*64 + xu*4,
                  lds + 8192 + bufb*2048 + xs*1024 + (wave&3)*256);
    }
}

// lane=(b0:3)(j:1)(og:2); wave owns n-rows {2w,2w+1}-staged W; batches b0,b0+8.
// PASS 0: s0 partial = sum_n u. PASS>0: c_j = sigmoid(sgn_j*d), d = 3 shuffles.
template<int PASS>
__global__ __launch_bounds__(TPB) void caps_pass(
    const float* __restrict__ x, const float* __restrict__ W,
    const float* __restrict__ vin, float* __restrict__ part, int grid)
{
    const int t = threadIdx.x;
    const int lane = t & 63;
    const int wave = t >> 6;
    const int og = lane & 3;
    const int j  = (lane >> 2) & 1;
    const int b0 = lane >> 3;
    const int bid = blockIdx.x;

    __shared__ __align__(16) float lds[12288];   // W dbuf 8192 + x dbuf 4096

    const float sgn = j ? -1.f : 1.f;

    f32x4 vinA = {0.f,0.f,0.f,0.f}, vinB = {0.f,0.f,0.f,0.f};
    if (PASS > 0) {
        vinA = sgn * *(const f32x4*)(vin + b0 * 32 + j * 16 + og * 4);
        vinB = sgn * *(const f32x4*)(vin + (b0 + 8) * 32 + j * 16 + og * 4);
    }

    f32x4 accA = {0.f,0.f,0.f,0.f};
    f32x4 accB = {0.f,0.f,0.f,0.f};

    const int R_rounds = (NCHUNK + 2*grid - 1) / (2*grid);

    issue_round(x, W, lds, bid, grid, 0, lane, wave);
    issue_round(x, W, lds, bid, grid, 1, lane, wave);

    for (int k = 0; k < R_rounds; ++k) {
        asm volatile("s_waitcnt vmcnt(3)" ::: "memory"); // set k done; k+1 in flight
        __builtin_amdgcn_s_barrier();                    // all waves staged

        const int bufb = k & 1;
        #pragma unroll
        for (int s = 0; s < 2; ++s) {
            const int c = bid + (2*k + s) * grid;
            if (c < NCHUNK) {                            // block-uniform guard
                const float* wrow = lds + bufb*4096 + s*2048
                                  + (j*8 + wave)*128 + og*4;
                const float* xrg  = lds + 8192 + bufb*2048 + s*1024;
                const int u0i = wave * 2;
                const int swz = (b0 & 7);

                f32x4 u0 = {0.f,0.f,0.f,0.f};
                f32x4 u1 = {0.f,0.f,0.f,0.f};
                {   // group 0: W i=0..3 with x units u0i
                    f32x4 W0,W1,W2,W3,XA,XB;
                    DSR128(W0, wrow + 0);
                    DSR128(W1, wrow + 16);
                    DSR128(W2, wrow + 32);
                    DSR128(W3, wrow + 48);
                    DSR128(XA, xrg + b0*64     + ((u0i^swz) << 2));
                    DSR128(XB, xrg + (b0+8)*64 + ((u0i^swz) << 2));
                    asm volatile("s_waitcnt lgkmcnt(0)");
                    __builtin_amdgcn_sched_barrier(0);
                    u0 += W0*XA.x; u0 += W1*XA.y; u0 += W2*XA.z; u0 += W3*XA.w;
                    u1 += W0*XB.x; u1 += W1*XB.y; u1 += W2*XB.z; u1 += W3*XB.w;
                }
                {   // group 1: W i=4..7 with x units u0i+1
                    f32x4 W4,W5,W6,W7,XC,XD;
                    DSR128(W4, wrow + 64);
                    DSR128(W5, wrow + 80);
                    DSR128(W6, wrow + 96);
                    DSR128(W7, wrow + 112);
                    DSR128(XC, xrg + b0*64     + (((u0i+1)^swz) << 2));
                    DSR128(XD, xrg + (b0+8)*64 + (((u0i+1)^swz) << 2));
                    asm volatile("s_waitcnt lgkmcnt(0)");
                    __builtin_amdgcn_sched_barrier(0);
                    u0 += W4*XC.x; u0 += W5*XC.y; u0 += W6*XC.z; u0 += W7*XC.w;
                    u1 += W4*XD.x; u1 += W5*XD.y; u1 += W6*XD.z; u1 += W7*XD.w;
                }

                if (PASS == 0) {
                    accA += u0;
                    accB += u1;
                } else {
                    float m0 = vinA.x*u0.x + vinA.y*u0.y + vinA.z*u0.z + vinA.w*u0.w;
                    float m1 = vinB.x*u1.x + vinB.y*u1.y + vinB.z*u1.z + vinB.w*u1.w;
                    m0 += __shfl_xor(m0, 1);  m1 += __shfl_xor(m1, 1);
                    m0 += __shfl_xor(m0, 2);  m1 += __shfl_xor(m1, 2);
                    m0 += __shfl_xor(m0, 4);  m1 += __shfl_xor(m1, 4);  // = d
                    const float cA = __builtin_amdgcn_rcpf(1.f + __expf(-sgn * m0));
                    const float cB = __builtin_amdgcn_rcpf(1.f + __expf(-sgn * m1));
                    accA += u0 * cA;
                    accB += u1 * cB;
                }
            }
        }
        // memory-clobber fence: ISSUE (LDS writes) cannot hoist above this
        asm volatile("s_waitcnt lgkmcnt(0)" ::: "memory");
        __builtin_amdgcn_s_barrier();                    // all waves done reading
        issue_round(x, W, lds, bid, grid, k + 2, lane, wave);
    }

    // drain all DMAs (incl. tail dummies) before aliasing lds for the reduce
    asm volatile("s_waitcnt vmcnt(0)" ::: "memory");
    __syncthreads();

    // ---- epilogue: cross-wave reduce (8 waves hold disjoint n partials) ----
    {
        float* sl = lds + wave * 576 + lane * 9;
        sl[0]=accA.x; sl[1]=accA.y; sl[2]=accA.z; sl[3]=accA.w;
        sl[4]=accB.x; sl[5]=accB.y; sl[6]=accB.z; sl[7]=accB.w;
    }
    __syncthreads();
    if (t < 64) {
        float s[8];
        #pragma unroll
        for (int q = 0; q < 8; ++q) s[q] = 0.f;
        #pragma unroll
        for (int w = 0; w < 8; ++w) {
            const float* p = lds + w * 576 + t * 9;
            #pragma unroll
            for (int q = 0; q < 8; ++q) s[q] += p[q];
        }
        const int tb0 = t >> 3, tj = (t >> 2) & 1, tog = t & 3;
        #pragma unroll
        for (int q = 0; q < 4; ++q) {
            part[(size_t)(tb0*32 + tj*16 + tog*4 + q) * grid + bid] = s[q];
            part[(size_t)((tb0+8)*32 + tj*16 + tog*4 + q) * grid + bid] = s[4+q];
        }
    }
}

// Reduce partials -> s[b,j,o], squash -> v. 32 blocks = one per (b,j).
// PASS 0: scale 0.5 (uniform softmax), write v0
// PASS 1: write v0+v1 (logits linear in accumulated v)
// PASS 2: write final v
template<int PASS>
__global__ __launch_bounds__(256) void caps_reduce(
    const float* __restrict__ part, const float* __restrict__ vprev,
    float* __restrict__ vout, int gridA)
{
    const int blk = blockIdx.x;
    const int b = blk >> 1, j = blk & 1;
    const int t = threadIdx.x;
    const int o = t & 15;
    const int ch = t >> 4;
    const size_t base = ((size_t)b * 32 + j * 16 + o) * gridA;
    float s = 0.f;
    for (int g = ch; g < gridA; g += 16) s += part[base + g];
    __shared__ float red[256];
    red[t] = s;
    __syncthreads();
    if (t < 16) {
        float sv = 0.f;
        #pragma unroll
        for (int c = 0; c < 16; ++c) sv += red[c * 16 + t];
        if (PASS == 0) sv *= 0.5f;
        float sq = sv * sv;
        sq += __shfl_xor(sq, 1);
        sq += __shfl_xor(sq, 2);
        sq += __shfl_xor(sq, 4);
        sq += __shfl_xor(sq, 8);
        const float sn = sq;
        float v = sv * sn / ((1.f + sn) * sqrtf(sn + 1e-7f));
        if (PASS == 1) v += vprev[b * 32 + j * 16 + o];
        vout[b * 32 + j * 16 + o] = v;
    }
}

extern "C" void kernel_launch(void* const* d_in, const int* in_sizes, int n_in,
                              void* d_out, int out_size, void* d_ws, size_t ws_size,
                              hipStream_t stream) {
    const float* x = (const float*)d_in[0];
    const float* W = (const float*)d_in[1];
    float* out = (float*)d_out;

    // grid clamped to workspace (part = 512*GRID floats)
    size_t maxg = (ws_size - 4096) / (512 * sizeof(float));
    int GRID = (int)(maxg < GRID_P ? maxg : GRID_P);
    if (GRID < 1) GRID = 1;

    float* part = (float*)d_ws;                       // 512*GRID floats (1.5 MB)
    float* v0   = part + (size_t)512 * GRID;          // 512
    float* vsum = v0 + 512;                           // 512

    caps_pass<0><<<GRID, TPB, 0, stream>>>(x, W, nullptr, part, GRID);
    caps_reduce<0><<<32, 256, 0, stream>>>(part, nullptr, v0, GRID);
    caps_pass<1><<<GRID, TPB, 0, stream>>>(x, W, v0, part, GRID);
    caps_reduce<1><<<32, 256, 0, stream>>>(part, v0, vsum, GRID);
    caps_pass<2><<<GRID, TPB, 0, stream>>>(x, W, vsum, part, GRID);
    caps_reduce<2><<<32, 256, 0, stream>>>(part, nullptr, out, GRID);
}